// Round 3
// baseline (179.525 us; speedup 1.0000x reference)
//
#include <hip/hip_runtime.h>
#include <hip/hip_bf16.h>

typedef __attribute__((ext_vector_type(8))) short bf16x8;
typedef __attribute__((ext_vector_type(4))) float f32x4;
typedef __attribute__((ext_vector_type(4))) unsigned short u16x4;

#define LOG2E 1.4426950408889634f
#define QSCALE 0.125f
#define EXP2(x) __builtin_amdgcn_exp2f(x)

static __device__ __forceinline__ unsigned short f2bf(float f) {
  __hip_bfloat16 h = __float2bfloat16(f);
  return __builtin_bit_cast(unsigned short, h);
}
static __device__ __forceinline__ bf16x8 ld16(const void* p) {
  return *(const bf16x8*)p;
}
static __device__ __forceinline__ void gload16(const void* g, void* l) {
  __builtin_amdgcn_global_load_lds(
      (const __attribute__((address_space(1))) void*)g,
      (__attribute__((address_space(3))) void*)l, 16, 0, 0);
}

// ---------------- fp32 -> bf16 convert (x) ---------------------------------------------------------
__global__ void cvt_bf16(const float* __restrict__ in, unsigned short* __restrict__ out)
{
  const int i = blockIdx.x * 256 + threadIdx.x;   // 4 elements per thread
  const float4 a = ((const float4*)in)[i];
  u16x4 o; o[0] = f2bf(a.x); o[1] = f2bf(a.y); o[2] = f2bf(a.z); o[3] = f2bf(a.w);
  ((u16x4*)out)[i] = o;
}

// ---------------- expand quaternion weights (fp32) -> dense [1024][1024] bf16 (N x K) --------------
__global__ void expand_weights(const float* __restrict__ Wq,
                               const float* __restrict__ Wk,
                               const float* __restrict__ Wv,
                               const float* __restrict__ Wo,
                               unsigned short* __restrict__ Mqkv,
                               unsigned short* __restrict__ Mo)
{
  const int n = threadIdx.x;      // 0..255
  const int o = blockIdx.x;       // 0..255
  const int mat = blockIdx.y;     // 0:q 1:k 2:v 3:o
  const float* W = (mat == 0) ? Wq : (mat == 1) ? Wk : (mat == 2) ? Wv : Wo;
  unsigned short* M = (mat < 3) ? (Mqkv + (size_t)mat * 1024 * 1024) : Mo;
  const float4 w = *(const float4*)(W + ((size_t)o * 256 + n) * 4);
  const unsigned short w0 = f2bf(w.x), w1 = f2bf(w.y), w2 = f2bf(w.z), w3 = f2bf(w.w);
#define NG(u) ((unsigned short)((u) ^ 0x8000))
  // L(w): row k, col j of the 4x4 block at M[4o+k][4n+j]
  u16x4 r0; r0[0] = w0;     r0[1] = NG(w1); r0[2] = NG(w2); r0[3] = NG(w3);
  u16x4 r1; r1[0] = w1;     r1[1] = w0;     r1[2] = NG(w3); r1[3] = w2;
  u16x4 r2; r2[0] = w2;     r2[1] = w3;     r2[2] = w0;     r2[3] = NG(w1);
  u16x4 r3; r3[0] = w3;     r3[1] = NG(w2); r3[2] = w1;     r3[3] = w0;
#undef NG
  unsigned short* dst = M + (size_t)(o * 4) * 1024 + n * 4;
  *(u16x4*)(dst)        = r0;
  *(u16x4*)(dst + 1024) = r1;
  *(u16x4*)(dst + 2048) = r2;
  *(u16x4*)(dst + 3072) = r3;
}

// ---------------- pack int32 mask -> bitmask [2048][32] words ----------------
__global__ void pack_mask(const int* __restrict__ mask, unsigned long long* __restrict__ bits)
{
  const int g = blockIdx.x * 256 + threadIdx.x;
  const unsigned long long w = __ballot(mask[g] != 0);
  if ((threadIdx.x & 63) == 0) bits[g >> 6] = w;
}

// ---------------- GEMM: C[t,e] = sum_k A[t,k] * Bm[e,k] + bias  ------------------------------------
// MODE 0: N=3072 fused q/k/v.  q,k -> [4096][1024] bf16 (q scaled by 1/8), v -> [32][64][2048] (V^T)
// MODE 1: N=1024, write fp32 [4096][1024] to fout (d_out)
template <int MODE>
__global__ void gemm_bt(const unsigned short* __restrict__ A,
                        const unsigned short* __restrict__ Bm,
                        const float* __restrict__ bias0,
                        const float* __restrict__ bias1,
                        const float* __restrict__ bias2,
                        unsigned short* __restrict__ out0,
                        unsigned short* __restrict__ out1,
                        unsigned short* __restrict__ out2,
                        float* __restrict__ fout)
{
  constexpr int K = 1024;
  __shared__ unsigned short As[128 * 64];
  __shared__ unsigned short Bs[128 * 64];
  const int tid = threadIdx.x;
  const int lane = tid & 63;
  const int wave = tid >> 6;
  const int bn = blockIdx.x, bm = blockIdx.y;
  const int wm = wave >> 1, wn = wave & 1;
  const int l15 = lane & 15, l4 = lane >> 4;

  f32x4 zero4 = {0.f, 0.f, 0.f, 0.f};
  f32x4 acc[4][4];
#pragma unroll
  for (int i = 0; i < 4; ++i)
#pragma unroll
    for (int j = 0; j < 4; ++j) acc[i][j] = zero4;

  for (int kk = 0; kk < K; kk += 64) {
#pragma unroll
    for (int c = 0; c < 4; ++c) {
      const int Lb = (wave * 4 + c) * 1024;       // uniform per-wave LDS dest
      const int L = Lb + lane * 16;               // byte this lane lands at
      const int row = L >> 7;                     // 128B per row (64 bf16)
      const int slot = (L >> 4) & 7;
      const int ss = slot ^ (row & 7);            // pre-swizzled source slot
      gload16(A + (size_t)(bm * 128 + row) * K + kk + ss * 8, (char*)As + Lb);
      gload16(Bm + (size_t)(bn * 128 + row) * K + kk + ss * 8, (char*)Bs + Lb);
    }
    __syncthreads();
#pragma unroll
    for (int ks = 0; ks < 2; ++ks) {
      bf16x8 af[4], bfr[4];
#pragma unroll
      for (int i = 0; i < 4; ++i) {
        const int ra = wm * 64 + i * 16 + l15;
        const int sa = (ks * 4 + l4) ^ (ra & 7);
        af[i] = ld16((const char*)As + ra * 128 + sa * 16);
        const int rb = wn * 64 + i * 16 + l15;
        const int sb = (ks * 4 + l4) ^ (rb & 7);
        bfr[i] = ld16((const char*)Bs + rb * 128 + sb * 16);
      }
#pragma unroll
      for (int i = 0; i < 4; ++i)
#pragma unroll
        for (int j = 0; j < 4; ++j)
          acc[i][j] = __builtin_amdgcn_mfma_f32_16x16x32_bf16(af[i], bfr[j], acc[i][j], 0, 0, 0);
    }
    __syncthreads();
  }

#pragma unroll
  for (int i = 0; i < 4; ++i) {
    const int t0 = bm * 128 + wm * 64 + i * 16 + l4 * 4;   // +r rows
#pragma unroll
    for (int j = 0; j < 4; ++j) {
      const int e = bn * 128 + wn * 64 + j * 16 + l15;
      f32x4 v = acc[i][j];
      if (MODE == 0) {
        const int which = e >> 10;   // block-uniform
        const int e1 = e & 1023;
        const float* bp = (which == 0) ? bias0 : (which == 1 ? bias1 : bias2);
        const float bias = bp[e1];
        if (which == 0) {
#pragma unroll
          for (int r = 0; r < 4; ++r)
            out0[(size_t)(t0 + r) * 1024 + e1] = f2bf((v[r] + bias) * QSCALE);
        } else if (which == 1) {
#pragma unroll
          for (int r = 0; r < 4; ++r)
            out1[(size_t)(t0 + r) * 1024 + e1] = f2bf(v[r] + bias);
        } else {
          const int h = e1 >> 6, d = e1 & 63;
          const int b = t0 >> 11, s = t0 & 2047;
          u16x4 pk;
#pragma unroll
          for (int r = 0; r < 4; ++r) pk[r] = f2bf(v[r] + bias);
          *(u16x4*)&out2[((size_t)((b * 16 + h) * 64 + d)) * 2048 + s] = pk;
        }
      } else {
        const float bias = bias0[e];
#pragma unroll
        for (int r = 0; r < 4; ++r)
          fout[(size_t)(t0 + r) * 1024 + e] = v[r] + bias;
      }
    }
  }
}

// ---------------- flash attention ------------------------------------------------------------------
// q,k: [4096][1024] bf16 (q pre-scaled), vt: [32][64][2048] bf16, bits: [2048][32] mask words
// ctx out: [4096][1024] bf16
__global__ void attn_fwd(const unsigned short* __restrict__ q,
                         const unsigned short* __restrict__ k,
                         const unsigned short* __restrict__ vt,
                         const unsigned long long* __restrict__ mbits,
                         unsigned short* __restrict__ ctx)
{
  constexpr int S = 2048, E = 1024;
  __shared__ unsigned short Ks[64 * 64];
  __shared__ unsigned short Vs[64 * 64];
  __shared__ unsigned short Ps[4][16 * 64];
  __shared__ unsigned long long Mw[64];
  const int qb = blockIdx.x;   // 0..31 q blocks of 64 rows
  const int bh = blockIdx.y;   // 0..31
  const int b = bh >> 4, h = bh & 15;
  const int tid = threadIdx.x, lane = tid & 63, wave = tid >> 6;
  const int l15 = lane & 15, l4 = lane >> 4;
  const int rbase = l4 * 4;

  bf16x8 aq[2];
  {
    const size_t roff = (size_t)(b * S + qb * 64 + wave * 16 + l15) * E + h * 64 + l4 * 8;
    aq[0] = ld16(q + roff);
    aq[1] = ld16(q + roff + 32);
  }

  f32x4 zero4 = {0.f, 0.f, 0.f, 0.f};
  f32x4 po[4];
  float m[4], l[4];
#pragma unroll
  for (int i = 0; i < 4; ++i) { po[i] = zero4; m[i] = -1e30f; l[i] = 0.f; }

  for (int kt = 0; kt < 32; ++kt) {
#pragma unroll
    for (int c = 0; c < 2; ++c) {
      const int Lb = (wave * 2 + c) * 1024;
      const int L = Lb + lane * 16;
      const int row = L >> 7, slot = (L >> 4) & 7, ss = slot ^ (row & 7);
      gload16(k + (size_t)(b * S + kt * 64 + row) * E + h * 64 + ss * 8, (char*)Ks + Lb);
      gload16(vt + (size_t)(bh * 64 + row) * S + kt * 64 + ss * 8, (char*)Vs + Lb);
    }
    if (tid < 64) Mw[tid] = mbits[(size_t)(qb * 64 + tid) * 32 + kt];
    __syncthreads();

    // scores: C[16 q-rows x 64 keys] for this wave
    f32x4 sc[4];
#pragma unroll
    for (int ni = 0; ni < 4; ++ni) {
      sc[ni] = zero4;
#pragma unroll
      for (int ks = 0; ks < 2; ++ks) {
        const int rb = ni * 16 + l15;
        const int sb = (ks * 4 + l4) ^ (rb & 7);
        sc[ni] = __builtin_amdgcn_mfma_f32_16x16x32_bf16(
            aq[ks], ld16((const char*)Ks + rb * 128 + sb * 16), sc[ni], 0, 0, 0);
      }
    }

    float al[4];
    float p[4][4];  // [ni][r]
#pragma unroll
    for (int r = 0; r < 4; ++r) {
      const unsigned long long w = Mw[wave * 16 + rbase + r];
      float v = -INFINITY;
#pragma unroll
      for (int ni = 0; ni < 4; ++ni) {
        float s2 = sc[ni][r] * LOG2E;
        if (!((w >> (ni * 16 + l15)) & 1ull)) s2 = -INFINITY;
        p[ni][r] = s2;
        v = fmaxf(v, s2);
      }
      v = fmaxf(v, __shfl_xor(v, 1, 64));
      v = fmaxf(v, __shfl_xor(v, 2, 64));
      v = fmaxf(v, __shfl_xor(v, 4, 64));
      v = fmaxf(v, __shfl_xor(v, 8, 64));
      const float mn = fmaxf(m[r], v);       // m stays finite (init -1e30)
      al[r] = EXP2(m[r] - mn);
      m[r] = mn;
      float rs = 0.f;
#pragma unroll
      for (int ni = 0; ni < 4; ++ni) {
        const float pv = EXP2(p[ni][r] - mn);  // masked: exp2(-inf)=0
        p[ni][r] = pv;
        rs += pv;
      }
      rs += __shfl_xor(rs, 1, 64);
      rs += __shfl_xor(rs, 2, 64);
      rs += __shfl_xor(rs, 4, 64);
      rs += __shfl_xor(rs, 8, 64);
      l[r] = l[r] * al[r] + rs;
    }

#pragma unroll
    for (int nd = 0; nd < 4; ++nd)
#pragma unroll
      for (int r = 0; r < 4; ++r) po[nd][r] *= al[r];

    // transpose P (C-layout) -> A-layout via per-wave swizzled LDS buffer
    unsigned short* Pw = Ps[wave];
#pragma unroll
    for (int ni = 0; ni < 4; ++ni)
#pragma unroll
      for (int r = 0; r < 4; ++r) {
        const int pr = rbase + r;
        const int key = ni * 16 + l15;
        const int byte = pr * 128 + (((key >> 3) ^ (pr & 7)) << 4) + (key & 7) * 2;
        *(unsigned short*)((char*)Pw + byte) = f2bf(p[ni][r]);
      }

    bf16x8 ap[2];
#pragma unroll
    for (int ks = 0; ks < 2; ++ks) {
      const int sa = (ks * 4 + l4) ^ (l15 & 7);
      ap[ks] = ld16((const char*)Pw + l15 * 128 + sa * 16);
    }
#pragma unroll
    for (int nd = 0; nd < 4; ++nd) {
#pragma unroll
      for (int ks = 0; ks < 2; ++ks) {
        const int rv = nd * 16 + l15;
        const int sb = (ks * 4 + l4) ^ (rv & 7);
        po[nd] = __builtin_amdgcn_mfma_f32_16x16x32_bf16(
            ap[ks], ld16((const char*)Vs + rv * 128 + sb * 16), po[nd], 0, 0, 0);
      }
    }
    __syncthreads();
  }

  float inv[4];
#pragma unroll
  for (int r = 0; r < 4; ++r) inv[r] = 1.f / l[r];
  const int srow0 = qb * 64 + wave * 16 + rbase;
#pragma unroll
  for (int nd = 0; nd < 4; ++nd)
#pragma unroll
    for (int r = 0; r < 4; ++r)
      ctx[(size_t)(b * S + srow0 + r) * E + h * 64 + nd * 16 + l15] = f2bf(po[nd][r] * inv[r]);
}

// ---------------- launch ---------------------------------------------------------------------------
extern "C" void kernel_launch(void* const* d_in, const int* in_sizes, int n_in,
                              void* d_out, int out_size, void* d_ws, size_t ws_size,
                              hipStream_t stream)
{
  const float* x  = (const float*)d_in[0];
  const int* mask = (const int*)d_in[1];
  const float* Wq = (const float*)d_in[2];
  const float* bq = (const float*)d_in[3];
  const float* Wk = (const float*)d_in[4];
  const float* bk = (const float*)d_in[5];
  const float* Wv = (const float*)d_in[6];
  const float* bv = (const float*)d_in[7];
  const float* Wo = (const float*)d_in[8];
  const float* bo = (const float*)d_in[9];

  char* ws = (char*)d_ws;
  unsigned short* Mqkv = (unsigned short*)(ws);                         // 6 MB
  unsigned short* Mo   = (unsigned short*)(ws + (6ull  << 20));         // 2 MB
  unsigned short* qb_  = (unsigned short*)(ws + (8ull  << 20));         // 8 MB
  unsigned short* kb_  = (unsigned short*)(ws + (16ull << 20));         // 8 MB
  unsigned short* vtb  = (unsigned short*)(ws + (24ull << 20));         // 8 MB
  unsigned short* ctx  = (unsigned short*)(ws + (32ull << 20));         // 8 MB
  unsigned long long* bits = (unsigned long long*)(ws + (40ull << 20)); // 512 KB
  unsigned short* xb   = (unsigned short*)(ws + (41ull << 20));         // 8 MB

  cvt_bf16<<<dim3(4096), 256, 0, stream>>>(x, xb);
  expand_weights<<<dim3(256, 4), 256, 0, stream>>>(Wq, Wk, Wv, Wo, Mqkv, Mo);
  pack_mask<<<dim3(16384), 256, 0, stream>>>(mask, bits);
  gemm_bt<0><<<dim3(24, 32), 256, 0, stream>>>(xb, Mqkv, bq, bk, bv, qb_, kb_, vtb, nullptr);
  attn_fwd<<<dim3(32, 32), 256, 0, stream>>>(qb_, kb_, vtb, bits, ctx);
  gemm_bt<1><<<dim3(8, 32), 256, 0, stream>>>(ctx, Mo, bo, bo, bo, nullptr, nullptr, nullptr,
                                              (float*)d_out);
}

// Round 4
// 152.679 us; speedup vs baseline: 1.1758x; 1.1758x over previous
//
#include <hip/hip_runtime.h>
#include <hip/hip_bf16.h>

typedef __attribute__((ext_vector_type(8))) short bf16x8;
typedef __attribute__((ext_vector_type(4))) float f32x4;
typedef __attribute__((ext_vector_type(16))) float f32x16;
typedef __attribute__((ext_vector_type(4))) unsigned short u16x4;
typedef __attribute__((ext_vector_type(4))) unsigned int u32x4;

#define LOG2E 1.4426950408889634f
#define SCLOG 0.18033688011118312f   /* 0.125 * LOG2E : fold softmax scale+log2e into q */
#define EXP2(x) __builtin_amdgcn_exp2f(x)

static __device__ __forceinline__ unsigned short f2bf(float f) {
  __hip_bfloat16 h = __float2bfloat16(f);
  return __builtin_bit_cast(unsigned short, h);
}
static __device__ __forceinline__ unsigned pk2(float lo, float hg) {
  return (unsigned)f2bf(lo) | ((unsigned)f2bf(hg) << 16);
}
static __device__ __forceinline__ bf16x8 ld16(const void* p) {
  return *(const bf16x8*)p;
}
static __device__ __forceinline__ void gload16(const void* g, void* l) {
  __builtin_amdgcn_global_load_lds(
      (const __attribute__((address_space(1))) void*)g,
      (__attribute__((address_space(3))) void*)l, 16, 0, 0);
}

// ---------------- fp32 -> bf16 convert (x) ---------------------------------------------------------
__global__ void cvt_bf16(const float* __restrict__ in, unsigned short* __restrict__ out)
{
  const int i = blockIdx.x * 256 + threadIdx.x;   // 4 elements per thread
  const float4 a = ((const float4*)in)[i];
  u16x4 o; o[0] = f2bf(a.x); o[1] = f2bf(a.y); o[2] = f2bf(a.z); o[3] = f2bf(a.w);
  ((u16x4*)out)[i] = o;
}

// ---------------- expand quaternion weights (fp32) -> dense [1024][1024] bf16 (N x K) --------------
__global__ void expand_weights(const float* __restrict__ Wq,
                               const float* __restrict__ Wk,
                               const float* __restrict__ Wv,
                               const float* __restrict__ Wo,
                               unsigned short* __restrict__ Mqkv,
                               unsigned short* __restrict__ Mo)
{
  const int n = threadIdx.x;      // 0..255
  const int o = blockIdx.x;       // 0..255
  const int mat = blockIdx.y;     // 0:q 1:k 2:v 3:o
  const float* W = (mat == 0) ? Wq : (mat == 1) ? Wk : (mat == 2) ? Wv : Wo;
  unsigned short* M = (mat < 3) ? (Mqkv + (size_t)mat * 1024 * 1024) : Mo;
  const float4 w = *(const float4*)(W + ((size_t)o * 256 + n) * 4);
  const unsigned short w0 = f2bf(w.x), w1 = f2bf(w.y), w2 = f2bf(w.z), w3 = f2bf(w.w);
#define NG(u) ((unsigned short)((u) ^ 0x8000))
  // L(w): row k, col j of the 4x4 block at M[4o+k][4n+j]
  u16x4 r0; r0[0] = w0;     r0[1] = NG(w1); r0[2] = NG(w2); r0[3] = NG(w3);
  u16x4 r1; r1[0] = w1;     r1[1] = w0;     r1[2] = NG(w3); r1[3] = w2;
  u16x4 r2; r2[0] = w2;     r2[1] = w3;     r2[2] = w0;     r2[3] = NG(w1);
  u16x4 r3; r3[0] = w3;     r3[1] = NG(w2); r3[2] = w1;     r3[3] = w0;
#undef NG
  unsigned short* dst = M + (size_t)(o * 4) * 1024 + n * 4;
  *(u16x4*)(dst)        = r0;
  *(u16x4*)(dst + 1024) = r1;
  *(u16x4*)(dst + 2048) = r2;
  *(u16x4*)(dst + 3072) = r3;
}

// ---------------- pack int32 mask -> bitmask [2048][32] words ----------------
__global__ void pack_mask(const int* __restrict__ mask, unsigned long long* __restrict__ bits)
{
  const int g = blockIdx.x * 256 + threadIdx.x;
  const unsigned long long w = __ballot(mask[g] != 0);
  if ((threadIdx.x & 63) == 0) bits[g >> 6] = w;
}

// ---------------- GEMM: C[t,e] = sum_k A[t,k] * Bm[e,k] + bias  ------------------------------------
// MODE 0: N=3072 fused q/k/v.  q,k -> [4096][1024] bf16 (q scaled by SCLOG), v -> [32][64][2048] V^T
// MODE 1: N=1024, write fp32 [4096][1024] to fout (d_out)
template <int MODE>
__global__ void gemm_bt(const unsigned short* __restrict__ A,
                        const unsigned short* __restrict__ Bm,
                        const float* __restrict__ bias0,
                        const float* __restrict__ bias1,
                        const float* __restrict__ bias2,
                        unsigned short* __restrict__ out0,
                        unsigned short* __restrict__ out1,
                        unsigned short* __restrict__ out2,
                        float* __restrict__ fout)
{
  constexpr int K = 1024;
  __shared__ unsigned short As[128 * 64];
  __shared__ unsigned short Bs[128 * 64];
  const int tid = threadIdx.x;
  const int lane = tid & 63;
  const int wave = tid >> 6;
  const int bn = blockIdx.x, bm = blockIdx.y;
  const int wm = wave >> 1, wn = wave & 1;
  const int l15 = lane & 15, l4 = lane >> 4;

  f32x4 zero4 = {0.f, 0.f, 0.f, 0.f};
  f32x4 acc[4][4];
#pragma unroll
  for (int i = 0; i < 4; ++i)
#pragma unroll
    for (int j = 0; j < 4; ++j) acc[i][j] = zero4;

  for (int kk = 0; kk < K; kk += 64) {
#pragma unroll
    for (int c = 0; c < 4; ++c) {
      const int Lb = (wave * 4 + c) * 1024;       // uniform per-wave LDS dest
      const int L = Lb + lane * 16;               // byte this lane lands at
      const int row = L >> 7;                     // 128B per row (64 bf16)
      const int slot = (L >> 4) & 7;
      const int ss = slot ^ (row & 7);            // pre-swizzled source slot
      gload16(A + (size_t)(bm * 128 + row) * K + kk + ss * 8, (char*)As + Lb);
      gload16(Bm + (size_t)(bn * 128 + row) * K + kk + ss * 8, (char*)Bs + Lb);
    }
    __syncthreads();
#pragma unroll
    for (int ks = 0; ks < 2; ++ks) {
      bf16x8 af[4], bfr[4];
#pragma unroll
      for (int i = 0; i < 4; ++i) {
        const int ra = wm * 64 + i * 16 + l15;
        const int sa = (ks * 4 + l4) ^ (ra & 7);
        af[i] = ld16((const char*)As + ra * 128 + sa * 16);
        const int rb = wn * 64 + i * 16 + l15;
        const int sb = (ks * 4 + l4) ^ (rb & 7);
        bfr[i] = ld16((const char*)Bs + rb * 128 + sb * 16);
      }
#pragma unroll
      for (int i = 0; i < 4; ++i)
#pragma unroll
        for (int j = 0; j < 4; ++j)
          acc[i][j] = __builtin_amdgcn_mfma_f32_16x16x32_bf16(af[i], bfr[j], acc[i][j], 0, 0, 0);
    }
    __syncthreads();
  }

#pragma unroll
  for (int i = 0; i < 4; ++i) {
    const int t0 = bm * 128 + wm * 64 + i * 16 + l4 * 4;   // +r rows
#pragma unroll
    for (int j = 0; j < 4; ++j) {
      const int e = bn * 128 + wn * 64 + j * 16 + l15;
      f32x4 v = acc[i][j];
      if (MODE == 0) {
        const int which = e >> 10;   // block-uniform
        const int e1 = e & 1023;
        const float* bp = (which == 0) ? bias0 : (which == 1 ? bias1 : bias2);
        const float bias = bp[e1];
        if (which == 0) {
#pragma unroll
          for (int r = 0; r < 4; ++r)
            out0[(size_t)(t0 + r) * 1024 + e1] = f2bf((v[r] + bias) * SCLOG);
        } else if (which == 1) {
#pragma unroll
          for (int r = 0; r < 4; ++r)
            out1[(size_t)(t0 + r) * 1024 + e1] = f2bf(v[r] + bias);
        } else {
          const int h = e1 >> 6, d = e1 & 63;
          const int b = t0 >> 11, s = t0 & 2047;
          u16x4 pk;
#pragma unroll
          for (int r = 0; r < 4; ++r) pk[r] = f2bf(v[r] + bias);
          *(u16x4*)&out2[((size_t)((b * 16 + h) * 64 + d)) * 2048 + s] = pk;
        }
      } else {
        const float bias = bias0[e];
#pragma unroll
        for (int r = 0; r < 4; ++r)
          fout[(size_t)(t0 + r) * 1024 + e] = v[r] + bias;
      }
    }
  }
}

// ---------------- flash attention, swapped-operand 32x32 -------------------------------------------
// q,k: [4096][1024] bf16 (q pre-scaled by 0.125*log2e), vt: [32][64][2048] bf16 (V^T)
// mbits: [2048][32] mask words. ctx out: [4096][1024] bf16.
// Block: 256 thr = 4 waves; wave owns 32 q-rows. Grid 512 (16 q-groups x 32 bh), XCD-swizzled.
// QK^T swapped: P^T[key][q] = mfma32(A=K, B=Q^T) -> lane pair (l, l+32) holds full 64-key row of
// q = lane&31. Softmax lane-local. PV: O^T[d][q] = mfma32(A=V^T, B=P^T), P^T built in-register.
__global__ void attn_fwd(const unsigned short* __restrict__ q,
                         const unsigned short* __restrict__ k,
                         const unsigned short* __restrict__ vt,
                         const unsigned long long* __restrict__ mbits,
                         unsigned short* __restrict__ ctx)
{
  constexpr int S = 2048;
  __shared__ __align__(16) unsigned short Ks[2 * 4096];  // [buf][64 keys][64 d], XOR-swizzled
  __shared__ __align__(16) unsigned short Vs[2 * 4096];  // [buf][64 d][64 keys], XOR-swizzled

  // XCD-bijective swizzle (512 % 8 == 0): consecutive virtual blocks share bh -> same K/V in L2
  const int bid = blockIdx.x;
  const int vb = (bid & 7) * 64 + (bid >> 3);
  const int qg = vb & 15;        // 0..15 : 128 q-rows
  const int bh = vb >> 4;        // 0..31
  const int b = bh >> 4, h = bh & 15;

  const int tid = threadIdx.x, lane = tid & 63, wave = tid >> 6;
  const int l31 = lane & 31, hif = lane >> 5;
  const int sq = qg * 128 + wave * 32 + l31;     // this lane's q sequence position
  const size_t gq = (size_t)b * S + sq;          // row in q/ctx matrices

  // Q^T B-fragments: B[k=16s + hif*8 + j][q=l31]
  bf16x8 bqf[4];
#pragma unroll
  for (int s = 0; s < 4; ++s)
    bqf[s] = ld16(q + gq * 1024 + h * 64 + s * 16 + hif * 8);

  f32x16 o0 = {}, o1 = {};
  float m = -1e30f, l = 0.f;

#define STAGE(bufi, kti)                                                                  \
  {                                                                                       \
    _Pragma("unroll")                                                                     \
    for (int c = 0; c < 2; ++c) {                                                         \
      const int sl = c * 256 + tid;                                                       \
      const int row = sl >> 3;                                                            \
      const int ss = (sl & 7) ^ (row & 7);                                                \
      gload16(k + (size_t)(b * S + (kti) * 64 + row) * 1024 + h * 64 + ss * 8,            \
              (char*)Ks + (bufi) * 8192 + (c * 4 + wave) * 1024);                         \
      gload16(vt + (size_t)(bh * 64 + row) * 2048 + (kti) * 64 + ss * 8,                  \
              (char*)Vs + (bufi) * 8192 + (c * 4 + wave) * 1024);                         \
    }                                                                                     \
  }

  STAGE(0, 0);
  __syncthreads();

  int buf = 0;
  for (int kt = 0; kt < 32; ++kt) {
    const unsigned long long w = mbits[(size_t)sq * 32 + kt];
    if (kt + 1 < 32) STAGE(buf ^ 1, kt + 1);

    // ---- QK^T: p0 = keys 0..31 (C rows), p1 = keys 32..63; col = q = l31
    const char* Kb = (const char*)Ks + buf * 8192;
    f32x16 p0 = {}, p1 = {};
#pragma unroll
    for (int s = 0; s < 4; ++s) {
      const int slot = s * 2 + hif;
      const int r0 = l31, r1 = 32 + l31;
      bf16x8 a0 = ld16(Kb + r0 * 128 + ((slot ^ (r0 & 7)) << 4));
      bf16x8 a1 = ld16(Kb + r1 * 128 + ((slot ^ (r1 & 7)) << 4));
      p0 = __builtin_amdgcn_mfma_f32_32x32x16_bf16(a0, bqf[s], p0, 0, 0, 0);
      p1 = __builtin_amdgcn_mfma_f32_32x32x16_bf16(a1, bqf[s], p1, 0, 0, 0);
    }

    // ---- mask (fast path: all ones)
    if (!__all(w == ~0ull)) {
#pragma unroll
      for (int c = 0; c < 16; ++c) {
        const int key = (c & 3) + 8 * (c >> 2) + 4 * hif;   // C-row for reg c
        if (!((w >> key) & 1ull)) p0[c] = -INFINITY;
        if (!((w >> (key + 32)) & 1ull)) p1[c] = -INFINITY;
      }
    }

    // ---- row max (lane-local 32 + pair exchange)
    float pm = fmaxf(p0[0], p1[0]);
#pragma unroll
    for (int c = 1; c < 16; ++c) pm = fmaxf(pm, fmaxf(p0[c], p1[c]));
    pm = fmaxf(pm, __shfl_xor(pm, 32, 64));

    // ---- defer-max rescale (THR=8 in log2 domain)
    if (pm > m + 8.f) {
      const float al = EXP2(m - pm);
      m = pm;
      l *= al;
#pragma unroll
      for (int c = 0; c < 16; ++c) { o0[c] *= al; o1[c] *= al; }
    }

    // ---- exp + row sum
    float ts = 0.f;
#pragma unroll
    for (int c = 0; c < 16; ++c) {
      p0[c] = EXP2(p0[c] - m);
      p1[c] = EXP2(p1[c] - m);
      ts += p0[c] + p1[c];
    }
    ts += __shfl_xor(ts, 32, 64);
    l += ts;

    // ---- build P^T B-fragments (16 keys each) in-register: pack + pair exchange
    u32x4 bpw[4];
#pragma unroll
    for (int ks = 0; ks < 4; ++ks) {
      const f32x16 ps = (ks < 2) ? p0 : p1;
      const int rb2 = (ks & 1) * 8;
      const unsigned a0 = pk2(ps[rb2 + 0], ps[rb2 + 1]);
      const unsigned a1 = pk2(ps[rb2 + 2], ps[rb2 + 3]);
      const unsigned a2 = pk2(ps[rb2 + 4], ps[rb2 + 5]);
      const unsigned a3 = pk2(ps[rb2 + 6], ps[rb2 + 7]);
      const unsigned x0 = (unsigned)__shfl_xor((int)a0, 32, 64);
      const unsigned x1 = (unsigned)__shfl_xor((int)a1, 32, 64);
      const unsigned x2 = (unsigned)__shfl_xor((int)a2, 32, 64);
      const unsigned x3 = (unsigned)__shfl_xor((int)a3, 32, 64);
      bpw[ks][0] = hif ? x2 : a0;
      bpw[ks][1] = hif ? x3 : a1;
      bpw[ks][2] = hif ? a2 : x0;
      bpw[ks][3] = hif ? a3 : x1;
    }

    // ---- PV: O^T[d][q] += V^T[d][key] * P^T[key][q]
    const char* Vb = (const char*)Vs + buf * 8192;
#pragma unroll
    for (int ks = 0; ks < 4; ++ks) {
      const bf16x8 bfrag = __builtin_bit_cast(bf16x8, bpw[ks]);
      const int slot = ks * 2 + hif;
      const int r0 = l31, r1 = 32 + l31;
      bf16x8 v0 = ld16(Vb + r0 * 128 + ((slot ^ (r0 & 7)) << 4));
      bf16x8 v1 = ld16(Vb + r1 * 128 + ((slot ^ (r1 & 7)) << 4));
      o0 = __builtin_amdgcn_mfma_f32_32x32x16_bf16(v0, bfrag, o0, 0, 0, 0);
      o1 = __builtin_amdgcn_mfma_f32_32x32x16_bf16(v1, bfrag, o1, 0, 0, 0);
    }

    __syncthreads();
    buf ^= 1;
  }
#undef STAGE

  // ---- epilogue: lane writes its q-row at 32 d positions (pairs packed to dwords)
  const float inv = 1.f / l;
#pragma unroll
  for (int r = 0; r < 16; r += 2) {
    const int d0 = (r & 3) + 8 * (r >> 2) + 4 * hif;
    *(unsigned*)(ctx + gq * 1024 + h * 64 + d0) = pk2(o0[r] * inv, o0[r + 1] * inv);
    *(unsigned*)(ctx + gq * 1024 + h * 64 + 32 + d0) = pk2(o1[r] * inv, o1[r + 1] * inv);
  }
}

// ---------------- launch ---------------------------------------------------------------------------
extern "C" void kernel_launch(void* const* d_in, const int* in_sizes, int n_in,
                              void* d_out, int out_size, void* d_ws, size_t ws_size,
                              hipStream_t stream)
{
  const float* x  = (const float*)d_in[0];
  const int* mask = (const int*)d_in[1];
  const float* Wq = (const float*)d_in[2];
  const float* bq = (const float*)d_in[3];
  const float* Wk = (const float*)d_in[4];
  const float* bk = (const float*)d_in[5];
  const float* Wv = (const float*)d_in[6];
  const float* bv = (const float*)d_in[7];
  const float* Wo = (const float*)d_in[8];
  const float* bo = (const float*)d_in[9];

  char* ws = (char*)d_ws;
  unsigned short* Mqkv = (unsigned short*)(ws);                         // 6 MB
  unsigned short* Mo   = (unsigned short*)(ws + (6ull  << 20));         // 2 MB
  unsigned short* qb_  = (unsigned short*)(ws + (8ull  << 20));         // 8 MB
  unsigned short* kb_  = (unsigned short*)(ws + (16ull << 20));         // 8 MB
  unsigned short* vtb  = (unsigned short*)(ws + (24ull << 20));         // 8 MB
  unsigned short* ctx  = (unsigned short*)(ws + (32ull << 20));         // 8 MB
  unsigned long long* bits = (unsigned long long*)(ws + (40ull << 20)); // 512 KB
  unsigned short* xb   = (unsigned short*)(ws + (41ull << 20));         // 8 MB

  cvt_bf16<<<dim3(4096), 256, 0, stream>>>(x, xb);
  expand_weights<<<dim3(256, 4), 256, 0, stream>>>(Wq, Wk, Wv, Wo, Mqkv, Mo);
  pack_mask<<<dim3(16384), 256, 0, stream>>>(mask, bits);
  gemm_bt<0><<<dim3(24, 32), 256, 0, stream>>>(xb, Mqkv, bq, bk, bv, qb_, kb_, vtb, nullptr);
  attn_fwd<<<dim3(512), 256, 0, stream>>>(qb_, kb_, vtb, bits, ctx);
  gemm_bt<1><<<dim3(8, 32), 256, 0, stream>>>(ctx, Mo, bo, bo, bo, nullptr, nullptr, nullptr,
                                              (float*)d_out);
}

// Round 5
// 136.055 us; speedup vs baseline: 1.3195x; 1.1222x over previous
//
#include <hip/hip_runtime.h>
#include <hip/hip_bf16.h>

typedef __attribute__((ext_vector_type(8))) short bf16x8;
typedef __attribute__((ext_vector_type(4))) float f32x4;
typedef __attribute__((ext_vector_type(16))) float f32x16;
typedef __attribute__((ext_vector_type(4))) unsigned short u16x4;
typedef __attribute__((ext_vector_type(4))) unsigned int u32x4;

#define LOG2E 1.4426950408889634f
#define SCLOG 0.18033688011118312f   /* 0.125 * LOG2E : fold softmax scale+log2e into q */
#define EXP2(x) __builtin_amdgcn_exp2f(x)

static __device__ __forceinline__ unsigned short f2bf(float f) {
  __hip_bfloat16 h = __float2bfloat16(f);
  return __builtin_bit_cast(unsigned short, h);
}
static __device__ __forceinline__ unsigned pk2(float lo, float hg) {
  return (unsigned)f2bf(lo) | ((unsigned)f2bf(hg) << 16);
}
static __device__ __forceinline__ bf16x8 ld16(const void* p) {
  return *(const bf16x8*)p;
}
static __device__ __forceinline__ void gload16(const void* g, void* l) {
  __builtin_amdgcn_global_load_lds(
      (const __attribute__((address_space(1))) void*)g,
      (__attribute__((address_space(3))) void*)l, 16, 0, 0);
}

// ---------------- fp32 -> bf16 convert (x) ---------------------------------------------------------
__global__ void cvt_bf16(const float* __restrict__ in, unsigned short* __restrict__ out)
{
  const int i = blockIdx.x * 256 + threadIdx.x;   // 4 elements per thread
  const float4 a = ((const float4*)in)[i];
  u16x4 o; o[0] = f2bf(a.x); o[1] = f2bf(a.y); o[2] = f2bf(a.z); o[3] = f2bf(a.w);
  ((u16x4*)out)[i] = o;
}

// ---------------- expand quaternion weights (fp32) -> dense [1024][1024] bf16 (N x K) --------------
__global__ void expand_weights(const float* __restrict__ Wq,
                               const float* __restrict__ Wk,
                               const float* __restrict__ Wv,
                               const float* __restrict__ Wo,
                               unsigned short* __restrict__ Mqkv,
                               unsigned short* __restrict__ Mo)
{
  const int n = threadIdx.x;      // 0..255
  const int o = blockIdx.x;       // 0..255
  const int mat = blockIdx.y;     // 0:q 1:k 2:v 3:o
  const float* W = (mat == 0) ? Wq : (mat == 1) ? Wk : (mat == 2) ? Wv : Wo;
  unsigned short* M = (mat < 3) ? (Mqkv + (size_t)mat * 1024 * 1024) : Mo;
  const float4 w = *(const float4*)(W + ((size_t)o * 256 + n) * 4);
  const unsigned short w0 = f2bf(w.x), w1 = f2bf(w.y), w2 = f2bf(w.z), w3 = f2bf(w.w);
#define NG(u) ((unsigned short)((u) ^ 0x8000))
  // L(w): row k, col j of the 4x4 block at M[4o+k][4n+j]
  u16x4 r0; r0[0] = w0;     r0[1] = NG(w1); r0[2] = NG(w2); r0[3] = NG(w3);
  u16x4 r1; r1[0] = w1;     r1[1] = w0;     r1[2] = NG(w3); r1[3] = w2;
  u16x4 r2; r2[0] = w2;     r2[1] = w3;     r2[2] = w0;     r2[3] = NG(w1);
  u16x4 r3; r3[0] = w3;     r3[1] = NG(w2); r3[2] = w1;     r3[3] = w0;
#undef NG
  unsigned short* dst = M + (size_t)(o * 4) * 1024 + n * 4;
  *(u16x4*)(dst)        = r0;
  *(u16x4*)(dst + 1024) = r1;
  *(u16x4*)(dst + 2048) = r2;
  *(u16x4*)(dst + 3072) = r3;
}

// ---------------- pack int32 mask -> bitmask [2048][32] words ----------------
__global__ void pack_mask(const int* __restrict__ mask, unsigned long long* __restrict__ bits)
{
  const int g = blockIdx.x * 256 + threadIdx.x;
  const unsigned long long w = __ballot(mask[g] != 0);
  if ((threadIdx.x & 63) == 0) bits[g >> 6] = w;
}

// ---------------- GEMM: C[t,e] = sum_k A[t,k] * Bm[e,k] + bias  ------------------------------------
// MODE 0: N=3072 fused q/k/v.  q,k -> [4096][1024] bf16 (q scaled by SCLOG), v -> [32][64][2048] V^T
// MODE 1: N=1024, write fp32 [4096][1024] to fout (d_out)
template <int MODE>
__global__ __launch_bounds__(256, 2)
void gemm_bt(const unsigned short* __restrict__ A,
             const unsigned short* __restrict__ Bm,
             const float* __restrict__ bias0,
             const float* __restrict__ bias1,
             const float* __restrict__ bias2,
             unsigned short* __restrict__ out0,
             unsigned short* __restrict__ out1,
             unsigned short* __restrict__ out2,
             float* __restrict__ fout)
{
  constexpr int K = 1024;
  __shared__ unsigned short As[128 * 64];
  __shared__ unsigned short Bs[128 * 64];
  const int tid = threadIdx.x;
  const int lane = tid & 63;
  const int wave = tid >> 6;
  const int bn = blockIdx.x, bm = blockIdx.y;
  const int wm = wave >> 1, wn = wave & 1;
  const int l15 = lane & 15, l4 = lane >> 4;

  f32x4 zero4 = {0.f, 0.f, 0.f, 0.f};
  f32x4 acc[4][4];
#pragma unroll
  for (int i = 0; i < 4; ++i)
#pragma unroll
    for (int j = 0; j < 4; ++j) acc[i][j] = zero4;

  for (int kk = 0; kk < K; kk += 64) {
#pragma unroll
    for (int c = 0; c < 4; ++c) {
      const int Lb = (wave * 4 + c) * 1024;       // uniform per-wave LDS dest
      const int L = Lb + lane * 16;               // byte this lane lands at
      const int row = L >> 7;                     // 128B per row (64 bf16)
      const int slot = (L >> 4) & 7;
      const int ss = slot ^ (row & 7);            // pre-swizzled source slot
      gload16(A + (size_t)(bm * 128 + row) * K + kk + ss * 8, (char*)As + Lb);
      gload16(Bm + (size_t)(bn * 128 + row) * K + kk + ss * 8, (char*)Bs + Lb);
    }
    __syncthreads();
#pragma unroll
    for (int ks = 0; ks < 2; ++ks) {
      bf16x8 af[4], bfr[4];
#pragma unroll
      for (int i = 0; i < 4; ++i) {
        const int ra = wm * 64 + i * 16 + l15;
        const int sa = (ks * 4 + l4) ^ (ra & 7);
        af[i] = ld16((const char*)As + ra * 128 + sa * 16);
        const int rb = wn * 64 + i * 16 + l15;
        const int sb = (ks * 4 + l4) ^ (rb & 7);
        bfr[i] = ld16((const char*)Bs + rb * 128 + sb * 16);
      }
#pragma unroll
      for (int i = 0; i < 4; ++i)
#pragma unroll
        for (int j = 0; j < 4; ++j)
          acc[i][j] = __builtin_amdgcn_mfma_f32_16x16x32_bf16(af[i], bfr[j], acc[i][j], 0, 0, 0);
    }
    __syncthreads();
  }

#pragma unroll
  for (int i = 0; i < 4; ++i) {
    const int t0 = bm * 128 + wm * 64 + i * 16 + l4 * 4;   // +r rows
#pragma unroll
    for (int j = 0; j < 4; ++j) {
      const int e = bn * 128 + wn * 64 + j * 16 + l15;
      f32x4 v = acc[i][j];
      if (MODE == 0) {
        const int which = e >> 10;   // block-uniform
        const int e1 = e & 1023;
        const float* bp = (which == 0) ? bias0 : (which == 1 ? bias1 : bias2);
        const float bias = bp[e1];
        if (which == 0) {
#pragma unroll
          for (int r = 0; r < 4; ++r)
            out0[(size_t)(t0 + r) * 1024 + e1] = f2bf((v[r] + bias) * SCLOG);
        } else if (which == 1) {
#pragma unroll
          for (int r = 0; r < 4; ++r)
            out1[(size_t)(t0 + r) * 1024 + e1] = f2bf(v[r] + bias);
        } else {
          const int h = e1 >> 6, d = e1 & 63;
          const int b = t0 >> 11, s = t0 & 2047;
          u16x4 pk;
#pragma unroll
          for (int r = 0; r < 4; ++r) pk[r] = f2bf(v[r] + bias);
          *(u16x4*)&out2[((size_t)((b * 16 + h) * 64 + d)) * 2048 + s] = pk;
        }
      } else {
        const float bias = bias0[e];
#pragma unroll
        for (int r = 0; r < 4; ++r)
          fout[(size_t)(t0 + r) * 1024 + e] = v[r] + bias;
      }
    }
  }
}

// ---------------- flash attention, swapped-operand 32x32 -------------------------------------------
// q,k: [4096][1024] bf16 (q pre-scaled by 0.125*log2e), vt: [32][64][2048] bf16 (V^T)
// mbits: [2048][32] mask words. ctx out: [4096][1024] bf16.
// Block: 256 thr = 4 waves; wave owns 32 q-rows. Grid 512 (16 q-groups x 32 bh), XCD-swizzled.
// QK^T swapped: P^T[key][q] = mfma32(A=K, B=Q^T) -> lane pair (l, l+32) holds full 64-key row of
// q = lane&31. Softmax lane-local. PV: O^T[d][q] = mfma32(A=V^T, B=P^T), P^T built in-register.
__global__ __launch_bounds__(256, 2)
void attn_fwd(const unsigned short* __restrict__ q,
              const unsigned short* __restrict__ k,
              const unsigned short* __restrict__ vt,
              const unsigned long long* __restrict__ mbits,
              unsigned short* __restrict__ ctx)
{
  constexpr int S = 2048;
  __shared__ __align__(16) unsigned short Ks[2 * 4096];  // [buf][64 keys][64 d], XOR-swizzled
  __shared__ __align__(16) unsigned short Vs[2 * 4096];  // [buf][64 d][64 keys], XOR-swizzled

  // XCD-bijective swizzle (512 % 8 == 0): consecutive virtual blocks share bh -> same K/V in L2
  const int bid = blockIdx.x;
  const int vb = (bid & 7) * 64 + (bid >> 3);
  const int qg = vb & 15;        // 0..15 : 128 q-rows
  const int bh = vb >> 4;        // 0..31
  const int b = bh >> 4, h = bh & 15;

  const int tid = threadIdx.x, lane = tid & 63, wave = tid >> 6;
  const int l31 = lane & 31, hif = lane >> 5;
  const int sq = qg * 128 + wave * 32 + l31;     // this lane's q sequence position
  const size_t gq = (size_t)b * S + sq;          // row in q/ctx matrices

  // Q^T B-fragments: B[k=16s + hif*8 + j][q=l31]
  bf16x8 bqf[4];
#pragma unroll
  for (int s = 0; s < 4; ++s)
    bqf[s] = ld16(q + gq * 1024 + h * 64 + s * 16 + hif * 8);

  f32x16 o0 = {}, o1 = {};
  float m = -1e30f, l = 0.f;

#define STAGE(bufi, kti)                                                                  \
  {                                                                                       \
    _Pragma("unroll")                                                                     \
    for (int c = 0; c < 2; ++c) {                                                         \
      const int sl = c * 256 + tid;                                                       \
      const int row = sl >> 3;                                                            \
      const int ss = (sl & 7) ^ (row & 7);                                                \
      gload16(k + (size_t)(b * S + (kti) * 64 + row) * 1024 + h * 64 + ss * 8,            \
              (char*)Ks + (bufi) * 8192 + (c * 4 + wave) * 1024);                         \
      gload16(vt + (size_t)(bh * 64 + row) * 2048 + (kti) * 64 + ss * 8,                  \
              (char*)Vs + (bufi) * 8192 + (c * 4 + wave) * 1024);                         \
    }                                                                                     \
  }

  STAGE(0, 0);
  __syncthreads();

  int buf = 0;
  for (int kt = 0; kt < 32; ++kt) {
    const unsigned long long w = mbits[(size_t)sq * 32 + kt];
    if (kt + 1 < 32) STAGE(buf ^ 1, kt + 1);

    // ---- QK^T: p0 = keys 0..31 (C rows), p1 = keys 32..63; col = q = l31
    const char* Kb = (const char*)Ks + buf * 8192;
    f32x16 p0 = {}, p1 = {};
#pragma unroll
    for (int s = 0; s < 4; ++s) {
      const int slot = s * 2 + hif;
      const int r0 = l31, r1 = 32 + l31;
      bf16x8 a0 = ld16(Kb + r0 * 128 + ((slot ^ (r0 & 7)) << 4));
      bf16x8 a1 = ld16(Kb + r1 * 128 + ((slot ^ (r1 & 7)) << 4));
      p0 = __builtin_amdgcn_mfma_f32_32x32x16_bf16(a0, bqf[s], p0, 0, 0, 0);
      p1 = __builtin_amdgcn_mfma_f32_32x32x16_bf16(a1, bqf[s], p1, 0, 0, 0);
    }

    // ---- mask (fast path: all ones)
    if (!__all(w == ~0ull)) {
#pragma unroll
      for (int c = 0; c < 16; ++c) {
        const int key = (c & 3) + 8 * (c >> 2) + 4 * hif;   // C-row for reg c
        if (!((w >> key) & 1ull)) p0[c] = -INFINITY;
        if (!((w >> (key + 32)) & 1ull)) p1[c] = -INFINITY;
      }
    }

    // ---- row max: depth-5 tree (16-wide) + pair exchange
    float mx[8];
#pragma unroll
    for (int c = 0; c < 8; ++c)
      mx[c] = fmaxf(fmaxf(p0[c], p0[c + 8]), fmaxf(p1[c], p1[c + 8]));
#pragma unroll
    for (int d = 4; d; d >>= 1)
#pragma unroll
      for (int c = 0; c < d; ++c) mx[c] = fmaxf(mx[c], mx[c + d]);
    const float pm = fmaxf(mx[0], __shfl_xor(mx[0], 32, 64));

    // ---- defer-max rescale (THR=8 in log2 domain)
    if (pm > m + 8.f) {
      const float al = EXP2(m - pm);
      m = pm;
      l *= al;
#pragma unroll
      for (int c = 0; c < 16; ++c) { o0[c] *= al; o1[c] *= al; }
    }

    // ---- exp + row sum (tree)
#pragma unroll
    for (int c = 0; c < 16; ++c) {
      p0[c] = EXP2(p0[c] - m);
      p1[c] = EXP2(p1[c] - m);
    }
    float sm[8];
#pragma unroll
    for (int c = 0; c < 8; ++c)
      sm[c] = (p0[c] + p0[c + 8]) + (p1[c] + p1[c + 8]);
#pragma unroll
    for (int d = 4; d; d >>= 1)
#pragma unroll
      for (int c = 0; c < d; ++c) sm[c] += sm[c + d];
    l += sm[0] + __shfl_xor(sm[0], 32, 64);

    // ---- build P^T B-fragments (16 keys each) in-register: pack + pair exchange
    u32x4 bpw[4];
#pragma unroll
    for (int ks = 0; ks < 4; ++ks) {
      const f32x16 ps = (ks < 2) ? p0 : p1;
      const int rb2 = (ks & 1) * 8;
      const unsigned a0 = pk2(ps[rb2 + 0], ps[rb2 + 1]);
      const unsigned a1 = pk2(ps[rb2 + 2], ps[rb2 + 3]);
      const unsigned a2 = pk2(ps[rb2 + 4], ps[rb2 + 5]);
      const unsigned a3 = pk2(ps[rb2 + 6], ps[rb2 + 7]);
      const unsigned x0 = (unsigned)__shfl_xor((int)a0, 32, 64);
      const unsigned x1 = (unsigned)__shfl_xor((int)a1, 32, 64);
      const unsigned x2 = (unsigned)__shfl_xor((int)a2, 32, 64);
      const unsigned x3 = (unsigned)__shfl_xor((int)a3, 32, 64);
      bpw[ks][0] = hif ? x2 : a0;
      bpw[ks][1] = hif ? x3 : a1;
      bpw[ks][2] = hif ? a2 : x0;
      bpw[ks][3] = hif ? a3 : x1;
    }

    // ---- PV: O^T[d][q] += V^T[d][key] * P^T[key][q]
    const char* Vb = (const char*)Vs + buf * 8192;
#pragma unroll
    for (int ks = 0; ks < 4; ++ks) {
      const bf16x8 bfrag = __builtin_bit_cast(bf16x8, bpw[ks]);
      const int slot = ks * 2 + hif;
      const int r0 = l31, r1 = 32 + l31;
      bf16x8 v0 = ld16(Vb + r0 * 128 + ((slot ^ (r0 & 7)) << 4));
      bf16x8 v1 = ld16(Vb + r1 * 128 + ((slot ^ (r1 & 7)) << 4));
      o0 = __builtin_amdgcn_mfma_f32_32x32x16_bf16(v0, bfrag, o0, 0, 0, 0);
      o1 = __builtin_amdgcn_mfma_f32_32x32x16_bf16(v1, bfrag, o1, 0, 0, 0);
    }

    __syncthreads();
    buf ^= 1;
  }
#undef STAGE

  // ---- epilogue: C-layout row = (r&3) + 8*(r>>2) + 4*hif -> 4 consecutive d per group, 8B stores
  const float inv = 1.f / l;
  unsigned short* cp = ctx + gq * 1024 + h * 64;
#pragma unroll
  for (int g = 0; g < 4; ++g) {
    u16x4 s0, s1;
#pragma unroll
    for (int t = 0; t < 4; ++t) {
      s0[t] = f2bf(o0[g * 4 + t] * inv);
      s1[t] = f2bf(o1[g * 4 + t] * inv);
    }
    *(u16x4*)(cp + g * 8 + hif * 4) = s0;
    *(u16x4*)(cp + 32 + g * 8 + hif * 4) = s1;
  }
}

// ---------------- launch ---------------------------------------------------------------------------
extern "C" void kernel_launch(void* const* d_in, const int* in_sizes, int n_in,
                              void* d_out, int out_size, void* d_ws, size_t ws_size,
                              hipStream_t stream)
{
  const float* x  = (const float*)d_in[0];
  const int* mask = (const int*)d_in[1];
  const float* Wq = (const float*)d_in[2];
  const float* bq = (const float*)d_in[3];
  const float* Wk = (const float*)d_in[4];
  const float* bk = (const float*)d_in[5];
  const float* Wv = (const float*)d_in[6];
  const float* bv = (const float*)d_in[7];
  const float* Wo = (const float*)d_in[8];
  const float* bo = (const float*)d_in[9];

  char* ws = (char*)d_ws;
  unsigned short* Mqkv = (unsigned short*)(ws);                         // 6 MB
  unsigned short* Mo   = (unsigned short*)(ws + (6ull  << 20));         // 2 MB
  unsigned short* qb_  = (unsigned short*)(ws + (8ull  << 20));         // 8 MB
  unsigned short* kb_  = (unsigned short*)(ws + (16ull << 20));         // 8 MB
  unsigned short* vtb  = (unsigned short*)(ws + (24ull << 20));         // 8 MB
  unsigned short* ctx  = (unsigned short*)(ws + (32ull << 20));         // 8 MB
  unsigned long long* bits = (unsigned long long*)(ws + (40ull << 20)); // 512 KB
  unsigned short* xb   = (unsigned short*)(ws + (41ull << 20));         // 8 MB

  cvt_bf16<<<dim3(4096), 256, 0, stream>>>(x, xb);
  expand_weights<<<dim3(256, 4), 256, 0, stream>>>(Wq, Wk, Wv, Wo, Mqkv, Mo);
  pack_mask<<<dim3(16384), 256, 0, stream>>>(mask, bits);
  gemm_bt<0><<<dim3(24, 32), 256, 0, stream>>>(xb, Mqkv, bq, bk, bv, qb_, kb_, vtb, nullptr);
  attn_fwd<<<dim3(512), 256, 0, stream>>>(qb_, kb_, vtb, bits, ctx);
  gemm_bt<1><<<dim3(8, 32), 256, 0, stream>>>(ctx, Mo, bo, bo, bo, nullptr, nullptr, nullptr,
                                              (float*)d_out);
}

// Round 6
// 129.681 us; speedup vs baseline: 1.3844x; 1.0492x over previous
//
#include <hip/hip_runtime.h>
#include <hip/hip_bf16.h>

typedef __attribute__((ext_vector_type(8))) short bf16x8;
typedef __attribute__((ext_vector_type(4))) float f32x4;
typedef __attribute__((ext_vector_type(16))) float f32x16;
typedef __attribute__((ext_vector_type(4))) unsigned short u16x4;
typedef __attribute__((ext_vector_type(4))) unsigned int u32x4;

#define LOG2E 1.4426950408889634f
#define SCLOG 0.18033688011118312f   /* 0.125 * LOG2E : fold softmax scale+log2e into q */
#define EXP2(x) __builtin_amdgcn_exp2f(x)

static __device__ __forceinline__ unsigned short f2bf(float f) {
  __hip_bfloat16 h = __float2bfloat16(f);
  return __builtin_bit_cast(unsigned short, h);
}
static __device__ __forceinline__ unsigned pk2(float lo, float hg) {
  return (unsigned)f2bf(lo) | ((unsigned)f2bf(hg) << 16);
}
static __device__ __forceinline__ bf16x8 ld16(const void* p) {
  return *(const bf16x8*)p;
}
static __device__ __forceinline__ void gload16(const void* g, void* l) {
  __builtin_amdgcn_global_load_lds(
      (const __attribute__((address_space(1))) void*)g,
      (__attribute__((address_space(3))) void*)l, 16, 0, 0);
}

// ---------------- fp32 -> bf16 convert (x) ---------------------------------------------------------
__global__ void cvt_bf16(const float* __restrict__ in, unsigned short* __restrict__ out)
{
  const int i = blockIdx.x * 256 + threadIdx.x;   // 4 elements per thread
  const float4 a = ((const float4*)in)[i];
  u16x4 o; o[0] = f2bf(a.x); o[1] = f2bf(a.y); o[2] = f2bf(a.z); o[3] = f2bf(a.w);
  ((u16x4*)out)[i] = o;
}

// ---------------- expand quaternion weights (fp32) -> dense [1024][1024] bf16 (N x K) --------------
__global__ void expand_weights(const float* __restrict__ Wq,
                               const float* __restrict__ Wk,
                               const float* __restrict__ Wv,
                               const float* __restrict__ Wo,
                               unsigned short* __restrict__ Mqkv,
                               unsigned short* __restrict__ Mo)
{
  const int n = threadIdx.x;      // 0..255
  const int o = blockIdx.x;       // 0..255
  const int mat = blockIdx.y;     // 0:q 1:k 2:v 3:o
  const float* W = (mat == 0) ? Wq : (mat == 1) ? Wk : (mat == 2) ? Wv : Wo;
  unsigned short* M = (mat < 3) ? (Mqkv + (size_t)mat * 1024 * 1024) : Mo;
  const float4 w = *(const float4*)(W + ((size_t)o * 256 + n) * 4);
  const unsigned short w0 = f2bf(w.x), w1 = f2bf(w.y), w2 = f2bf(w.z), w3 = f2bf(w.w);
#define NG(u) ((unsigned short)((u) ^ 0x8000))
  // L(w): row k, col j of the 4x4 block at M[4o+k][4n+j]
  u16x4 r0; r0[0] = w0;     r0[1] = NG(w1); r0[2] = NG(w2); r0[3] = NG(w3);
  u16x4 r1; r1[0] = w1;     r1[1] = w0;     r1[2] = NG(w3); r1[3] = w2;
  u16x4 r2; r2[0] = w2;     r2[1] = w3;     r2[2] = w0;     r2[3] = NG(w1);
  u16x4 r3; r3[0] = w3;     r3[1] = NG(w2); r3[2] = w1;     r3[3] = w0;
#undef NG
  unsigned short* dst = M + (size_t)(o * 4) * 1024 + n * 4;
  *(u16x4*)(dst)        = r0;
  *(u16x4*)(dst + 1024) = r1;
  *(u16x4*)(dst + 2048) = r2;
  *(u16x4*)(dst + 3072) = r3;
}

// ---------------- pack int32 mask -> bitmask [2048][32] words ----------------
__global__ void pack_mask(const int* __restrict__ mask, unsigned long long* __restrict__ bits)
{
  const int g = blockIdx.x * 256 + threadIdx.x;
  const unsigned long long w = __ballot(mask[g] != 0);
  if ((threadIdx.x & 63) == 0) bits[g >> 6] = w;
}

// ---------------- GEMM: C[t,e] = sum_k A[t,k] * Bm[e,k] + bias  ------------------------------------
// MODE 0: N=3072 fused q/k/v.  q,k -> [4096][1024] bf16 (q scaled by SCLOG), v -> [32][64][2048] V^T
// MODE 1: N=1024, write fp32 [4096][1024] to fout (d_out)
template <int MODE>
__global__ __launch_bounds__(256, 3)
void gemm_bt(const unsigned short* __restrict__ A,
             const unsigned short* __restrict__ Bm,
             const float* __restrict__ bias0,
             const float* __restrict__ bias1,
             const float* __restrict__ bias2,
             unsigned short* __restrict__ out0,
             unsigned short* __restrict__ out1,
             unsigned short* __restrict__ out2,
             float* __restrict__ fout)
{
  constexpr int K = 1024;
  __shared__ unsigned short As[128 * 64];
  __shared__ unsigned short Bs[128 * 64];
  const int tid = threadIdx.x;
  const int lane = tid & 63;
  const int wave = tid >> 6;
  const int bn = blockIdx.x, bm = blockIdx.y;
  const int wm = wave >> 1, wn = wave & 1;
  const int l15 = lane & 15, l4 = lane >> 4;

  f32x4 zero4 = {0.f, 0.f, 0.f, 0.f};
  f32x4 acc[4][4];
#pragma unroll
  for (int i = 0; i < 4; ++i)
#pragma unroll
    for (int j = 0; j < 4; ++j) acc[i][j] = zero4;

  for (int kk = 0; kk < K; kk += 64) {
#pragma unroll
    for (int c = 0; c < 4; ++c) {
      const int Lb = (wave * 4 + c) * 1024;       // uniform per-wave LDS dest
      const int L = Lb + lane * 16;               // byte this lane lands at
      const int row = L >> 7;                     // 128B per row (64 bf16)
      const int slot = (L >> 4) & 7;
      const int ss = slot ^ (row & 7);            // pre-swizzled source slot
      gload16(A + (size_t)(bm * 128 + row) * K + kk + ss * 8, (char*)As + Lb);
      gload16(Bm + (size_t)(bn * 128 + row) * K + kk + ss * 8, (char*)Bs + Lb);
    }
    __syncthreads();
#pragma unroll
    for (int ks = 0; ks < 2; ++ks) {
      bf16x8 af[4], bfr[4];
#pragma unroll
      for (int i = 0; i < 4; ++i) {
        const int ra = wm * 64 + i * 16 + l15;
        const int sa = (ks * 4 + l4) ^ (ra & 7);
        af[i] = ld16((const char*)As + ra * 128 + sa * 16);
        const int rb = wn * 64 + i * 16 + l15;
        const int sb = (ks * 4 + l4) ^ (rb & 7);
        bfr[i] = ld16((const char*)Bs + rb * 128 + sb * 16);
      }
#pragma unroll
      for (int i = 0; i < 4; ++i)
#pragma unroll
        for (int j = 0; j < 4; ++j)
          acc[i][j] = __builtin_amdgcn_mfma_f32_16x16x32_bf16(af[i], bfr[j], acc[i][j], 0, 0, 0);
    }
    __syncthreads();
  }

#pragma unroll
  for (int i = 0; i < 4; ++i) {
    const int t0 = bm * 128 + wm * 64 + i * 16 + l4 * 4;   // +r rows
#pragma unroll
    for (int j = 0; j < 4; ++j) {
      const int e = bn * 128 + wn * 64 + j * 16 + l15;
      f32x4 v = acc[i][j];
      if (MODE == 0) {
        const int which = e >> 10;   // block-uniform
        const int e1 = e & 1023;
        const float* bp = (which == 0) ? bias0 : (which == 1 ? bias1 : bias2);
        const float bias = bp[e1];
        if (which == 0) {
#pragma unroll
          for (int r = 0; r < 4; ++r)
            out0[(size_t)(t0 + r) * 1024 + e1] = f2bf((v[r] + bias) * SCLOG);
        } else if (which == 1) {
#pragma unroll
          for (int r = 0; r < 4; ++r)
            out1[(size_t)(t0 + r) * 1024 + e1] = f2bf(v[r] + bias);
        } else {
          const int h = e1 >> 6, d = e1 & 63;
          const int b = t0 >> 11, s = t0 & 2047;
          u16x4 pk;
#pragma unroll
          for (int r = 0; r < 4; ++r) pk[r] = f2bf(v[r] + bias);
          *(u16x4*)&out2[((size_t)((b * 16 + h) * 64 + d)) * 2048 + s] = pk;
        }
      } else {
        const float bias = bias0[e];
#pragma unroll
        for (int r = 0; r < 4; ++r)
          fout[(size_t)(t0 + r) * 1024 + e] = v[r] + bias;
      }
    }
  }
}

// ---------------- flash attention, swapped-operand 32x32 -------------------------------------------
// q,k: [4096][1024] bf16 (q pre-scaled by 0.125*log2e), vt: [32][64][2048] bf16 (V^T)
// mbits: [2048][32] mask words. ctx out: [4096][1024] bf16.
// Block: 256 thr = 4 waves; wave owns 32 q-rows. Grid 512 (16 q-groups x 32 bh), XCD-swizzled.
// QK^T swapped: P^T[key][q] = mfma32(A=K, B=Q^T) -> lane pair (l, l+32) holds full 64-key row of
// q = lane&31. Softmax lane-local. PV: O^T[d][q] = mfma32(A=V^T, B=P^T), P^T built in-register
// via v_permlane32_swap_b32 (T12 primitive).
__global__ __launch_bounds__(256, 3)
void attn_fwd(const unsigned short* __restrict__ q,
              const unsigned short* __restrict__ k,
              const unsigned short* __restrict__ vt,
              const unsigned long long* __restrict__ mbits,
              unsigned short* __restrict__ ctx)
{
  constexpr int S = 2048;
  __shared__ __align__(16) unsigned short Ks[2 * 4096];  // [buf][64 keys][64 d], XOR-swizzled
  __shared__ __align__(16) unsigned short Vs[2 * 4096];  // [buf][64 d][64 keys], XOR-swizzled

  // XCD-bijective swizzle (512 % 8 == 0): consecutive virtual blocks share bh -> same K/V in L2
  const int bid = blockIdx.x;
  const int vb = (bid & 7) * 64 + (bid >> 3);
  const int qg = vb & 15;        // 0..15 : 128 q-rows
  const int bh = vb >> 4;        // 0..31
  const int b = bh >> 4, h = bh & 15;

  const int tid = threadIdx.x, lane = tid & 63, wave = tid >> 6;
  const int l31 = lane & 31, hif = lane >> 5;
  const int sq = qg * 128 + wave * 32 + l31;     // this lane's q sequence position
  const size_t gq = (size_t)b * S + sq;          // row in q/ctx matrices

  // Q^T B-fragments: B[k=16s + hif*8 + j][q=l31]
  bf16x8 bqf[4];
#pragma unroll
  for (int s = 0; s < 4; ++s)
    bqf[s] = ld16(q + gq * 1024 + h * 64 + s * 16 + hif * 8);

  f32x16 o0 = {}, o1 = {};
  float m = -1e30f, l = 0.f;

#define STAGE(bufi, kti)                                                                  \
  {                                                                                       \
    _Pragma("unroll")                                                                     \
    for (int c = 0; c < 2; ++c) {                                                         \
      const int sl = c * 256 + tid;                                                       \
      const int row = sl >> 3;                                                            \
      const int ss = (sl & 7) ^ (row & 7);                                                \
      gload16(k + (size_t)(b * S + (kti) * 64 + row) * 1024 + h * 64 + ss * 8,            \
              (char*)Ks + (bufi) * 8192 + (c * 4 + wave) * 1024);                         \
      gload16(vt + (size_t)(bh * 64 + row) * 2048 + (kti) * 64 + ss * 8,                  \
              (char*)Vs + (bufi) * 8192 + (c * 4 + wave) * 1024);                         \
    }                                                                                     \
  }

  STAGE(0, 0);
  __syncthreads();

  int buf = 0;
  for (int kt = 0; kt < 32; ++kt) {
    const unsigned long long w = mbits[(size_t)sq * 32 + kt];
    if (kt + 1 < 32) STAGE(buf ^ 1, kt + 1);

    // ---- QK^T: p0 = keys 0..31 (C rows), p1 = keys 32..63; col = q = l31
    const char* Kb = (const char*)Ks + buf * 8192;
    f32x16 p0 = {}, p1 = {};
#pragma unroll
    for (int s = 0; s < 4; ++s) {
      const int slot = s * 2 + hif;
      const int r0 = l31, r1 = 32 + l31;
      bf16x8 a0 = ld16(Kb + r0 * 128 + ((slot ^ (r0 & 7)) << 4));
      bf16x8 a1 = ld16(Kb + r1 * 128 + ((slot ^ (r1 & 7)) << 4));
      p0 = __builtin_amdgcn_mfma_f32_32x32x16_bf16(a0, bqf[s], p0, 0, 0, 0);
      p1 = __builtin_amdgcn_mfma_f32_32x32x16_bf16(a1, bqf[s], p1, 0, 0, 0);
    }

    // ---- mask (fast path: all ones)
    if (!__all(w == ~0ull)) {
#pragma unroll
      for (int c = 0; c < 16; ++c) {
        const int key = (c & 3) + 8 * (c >> 2) + 4 * hif;   // C-row for reg c
        if (!((w >> key) & 1ull)) p0[c] = -INFINITY;
        if (!((w >> (key + 32)) & 1ull)) p1[c] = -INFINITY;
      }
    }

    // ---- row max: depth-5 tree (16-wide) + pair exchange
    float mx[8];
#pragma unroll
    for (int c = 0; c < 8; ++c)
      mx[c] = fmaxf(fmaxf(p0[c], p0[c + 8]), fmaxf(p1[c], p1[c + 8]));
#pragma unroll
    for (int d = 4; d; d >>= 1)
#pragma unroll
      for (int c = 0; c < d; ++c) mx[c] = fmaxf(mx[c], mx[c + d]);
    const float pm = fmaxf(mx[0], __shfl_xor(mx[0], 32, 64));

    // ---- defer-max rescale (THR=8 in log2 domain)
    if (pm > m + 8.f) {
      const float al = EXP2(m - pm);
      m = pm;
      l *= al;
#pragma unroll
      for (int c = 0; c < 16; ++c) { o0[c] *= al; o1[c] *= al; }
    }

    // ---- exp + row sum (tree)
#pragma unroll
    for (int c = 0; c < 16; ++c) {
      p0[c] = EXP2(p0[c] - m);
      p1[c] = EXP2(p1[c] - m);
    }
    float sm[8];
#pragma unroll
    for (int c = 0; c < 8; ++c)
      sm[c] = (p0[c] + p0[c + 8]) + (p1[c] + p1[c + 8]);
#pragma unroll
    for (int d = 4; d; d >>= 1)
#pragma unroll
      for (int c = 0; c < d; ++c) sm[c] += sm[c + d];
    l += sm[0] + __shfl_xor(sm[0], 32, 64);

    // ---- build P^T B-fragments in-register: pack + v_permlane32_swap_b32
    // swap(X, Y): X' = {X.lo | Y.lo-from-partner}, Y' = {X.hi-from-partner | Y.hi}
    // X=pk2(r0,r1), Y=pk2(r4,r5) -> X' is frag word0 (both halves), Y' is word2.
    u32x4 bpw[4];
#pragma unroll
    for (int ks = 0; ks < 4; ++ks) {
      const f32x16 ps = (ks < 2) ? p0 : p1;
      const int rb2 = (ks & 1) * 8;
      unsigned X0 = pk2(ps[rb2 + 0], ps[rb2 + 1]);
      unsigned X1 = pk2(ps[rb2 + 2], ps[rb2 + 3]);
      unsigned Y0 = pk2(ps[rb2 + 4], ps[rb2 + 5]);
      unsigned Y1 = pk2(ps[rb2 + 6], ps[rb2 + 7]);
      asm("v_permlane32_swap_b32 %0, %1" : "+v"(X0), "+v"(Y0));
      asm("v_permlane32_swap_b32 %0, %1" : "+v"(X1), "+v"(Y1));
      bpw[ks][0] = X0;
      bpw[ks][1] = X1;
      bpw[ks][2] = Y0;
      bpw[ks][3] = Y1;
    }

    // ---- PV: O^T[d][q] += V^T[d][key] * P^T[key][q]
    const char* Vb = (const char*)Vs + buf * 8192;
#pragma unroll
    for (int ks = 0; ks < 4; ++ks) {
      const bf16x8 bfrag = __builtin_bit_cast(bf16x8, bpw[ks]);
      const int slot = ks * 2 + hif;
      const int r0 = l31, r1 = 32 + l31;
      bf16x8 v0 = ld16(Vb + r0 * 128 + ((slot ^ (r0 & 7)) << 4));
      bf16x8 v1 = ld16(Vb + r1 * 128 + ((slot ^ (r1 & 7)) << 4));
      o0 = __builtin_amdgcn_mfma_f32_32x32x16_bf16(v0, bfrag, o0, 0, 0, 0);
      o1 = __builtin_amdgcn_mfma_f32_32x32x16_bf16(v1, bfrag, o1, 0, 0, 0);
    }

    __syncthreads();
    buf ^= 1;
  }
#undef STAGE

  // ---- epilogue: C-layout row = (r&3) + 8*(r>>2) + 4*hif -> 4 consecutive d per group, 8B stores
  const float inv = 1.f / l;
  unsigned short* cp = ctx + gq * 1024 + h * 64;
#pragma unroll
  for (int g = 0; g < 4; ++g) {
    u16x4 s0, s1;
#pragma unroll
    for (int t = 0; t < 4; ++t) {
      s0[t] = f2bf(o0[g * 4 + t] * inv);
      s1[t] = f2bf(o1[g * 4 + t] * inv);
    }
    *(u16x4*)(cp + g * 8 + hif * 4) = s0;
    *(u16x4*)(cp + 32 + g * 8 + hif * 4) = s1;
  }
}

// ---------------- launch ---------------------------------------------------------------------------
extern "C" void kernel_launch(void* const* d_in, const int* in_sizes, int n_in,
                              void* d_out, int out_size, void* d_ws, size_t ws_size,
                              hipStream_t stream)
{
  const float* x  = (const float*)d_in[0];
  const int* mask = (const int*)d_in[1];
  const float* Wq = (const float*)d_in[2];
  const float* bq = (const float*)d_in[3];
  const float* Wk = (const float*)d_in[4];
  const float* bk = (const float*)d_in[5];
  const float* Wv = (const float*)d_in[6];
  const float* bv = (const float*)d_in[7];
  const float* Wo = (const float*)d_in[8];
  const float* bo = (const float*)d_in[9];

  char* ws = (char*)d_ws;
  unsigned short* Mqkv = (unsigned short*)(ws);                         // 6 MB
  unsigned short* Mo   = (unsigned short*)(ws + (6ull  << 20));         // 2 MB
  unsigned short* qb_  = (unsigned short*)(ws + (8ull  << 20));         // 8 MB
  unsigned short* kb_  = (unsigned short*)(ws + (16ull << 20));         // 8 MB
  unsigned short* vtb  = (unsigned short*)(ws + (24ull << 20));         // 8 MB
  unsigned short* ctx  = (unsigned short*)(ws + (32ull << 20));         // 8 MB
  unsigned long long* bits = (unsigned long long*)(ws + (40ull << 20)); // 512 KB
  unsigned short* xb   = (unsigned short*)(ws + (41ull << 20));         // 8 MB

  cvt_bf16<<<dim3(4096), 256, 0, stream>>>(x, xb);
  expand_weights<<<dim3(256, 4), 256, 0, stream>>>(Wq, Wk, Wv, Wo, Mqkv, Mo);
  pack_mask<<<dim3(16384), 256, 0, stream>>>(mask, bits);
  gemm_bt<0><<<dim3(24, 32), 256, 0, stream>>>(xb, Mqkv, bq, bk, bv, qb_, kb_, vtb, nullptr);
  attn_fwd<<<dim3(512), 256, 0, stream>>>(qb_, kb_, vtb, bits, ctx);
  gemm_bt<1><<<dim3(8, 32), 256, 0, stream>>>(ctx, Mo, bo, bo, bo, nullptr, nullptr, nullptr,
                                              (float*)d_out);
}